// Round 4
// baseline (535.878 us; speedup 1.0000x reference)
//
#include <hip/hip_runtime.h>
#include <hip/hip_bf16.h>
#include <stdint.h>

#define HD 1024
#define SEQ 2048
#define NC 32

typedef __bf16 bf16x4 __attribute__((ext_vector_type(4)));
typedef __bf16 bf16x8 __attribute__((ext_vector_type(8)));
typedef float f32x4 __attribute__((ext_vector_type(4)));

__device__ inline unsigned short f2bf(float f) {
  union { float f; unsigned int u; } v; v.f = f;
  unsigned int r = v.u + 0x7fffu + ((v.u >> 16) & 1u);
  return (unsigned short)(r >> 16);
}
// packed fp32x2 -> bf16x2 (v_cvt_pk_bf16_f32 on gfx950)
__device__ inline unsigned int pkcvt(float a, float b) {
  __hip_bfloat162 h = __float22bfloat162_rn(make_float2(a, b));
  union { __hip_bfloat162 h; unsigned int u; } v; v.h = h;
  return v.u;
}
__device__ inline uint4 pack8(float4 x, float4 y) {
  return make_uint4(pkcvt(x.x, x.y), pkcvt(x.z, x.w), pkcvt(y.x, y.y), pkcvt(y.z, y.w));
}
__device__ inline bf16x8 ld_frag8(const unsigned short* p) {
  bf16x4 lo = *(const bf16x4*)p;
  bf16x4 hi = *(const bf16x4*)(p + 4);
  return __builtin_shufflevector(lo, hi, 0, 1, 2, 3, 4, 5, 6, 7);
}
__device__ inline void glds16(const unsigned short* g, unsigned short* l) {
  __builtin_amdgcn_global_load_lds(
      (const __attribute__((address_space(1))) unsigned int*)g,
      (__attribute__((address_space(3))) unsigned int*)l, 16, 0, 0);
}

// ---------------- zero rows s<63 of output (fp32) ----------------
__global__ __launch_bounds__(256) void zero_head_kernel(float* __restrict__ out) {
  int i = (blockIdx.x * 256 + threadIdx.x) * 4;
  int b = i / 64512;
  int r = i - b * 64512;
  *(float4*)(out + (size_t)b * (SEQ * HD) + r) = make_float4(0.f, 0.f, 0.f, 0.f);
}

// ---------------- fp32 -> bf16 streaming convert (weights) ----------------
__global__ __launch_bounds__(256) void cvt_kernel(const float* __restrict__ in,
                                                  unsigned short* __restrict__ out, int n8) {
  int i = blockIdx.x * 256 + threadIdx.x;
  if (i < n8) {
    float4 a = ((const float4*)in)[(size_t)i * 2];
    float4 b = ((const float4*)in)[(size_t)i * 2 + 1];
    ((uint4*)out)[i] = pack8(a, b);
  }
}

// ---------------- fused K+V GEMM: fp32 A (kv), bf16 W via glds ----------------
// Kp normal layout; Vt transposed per (bc,head): Vt[((bc*16+h)*64+d)*256 + j]
__global__ __launch_bounds__(256, 2) void gemm_kv_kernel(
    const float* __restrict__ A, const unsigned short* __restrict__ Wkb,
    const unsigned short* __restrict__ Wvb, const float* __restrict__ bk,
    const float* __restrict__ bv, unsigned short* __restrict__ Kp,
    unsigned short* __restrict__ Vt) {
  __shared__ unsigned short lds_a[128 * 32];
  __shared__ unsigned short lds_bk[128 * 32];
  __shared__ unsigned short lds_bv[128 * 32];
  const int t = threadIdx.x;
  const int l = t & 63, w = t >> 6;
  const int wm = w >> 1, wn = w & 1;
  const int lr = l & 15, lq = l >> 4;
  // XCD-aware swizzle: 2048 blocks = 8 XCD x (32 M x 8 N); consecutive locals
  // on one XCD cover all 8 N-blocks of one A-tile -> A L2-resident, fetched ~once.
  const int bid = blockIdx.x;
  const int xcd = bid & 7, local = bid >> 3;
  const int nblk = local & 7, mblk = xcd * 32 + (local >> 3);
  const size_t arow0 = (size_t)mblk * 128;
  const size_t brow0 = (size_t)nblk * 128;
  const int c0 = t, c1 = 256 + t;
  const float* a0 = A + (arow0 + (c0 >> 2)) * HD + (c0 & 3) * 8;
  const float* a1 = A + (arow0 + (c1 >> 2)) * HD + (c1 & 3) * 8;
  const unsigned short* bk0 = Wkb + (brow0 + (c0 >> 2)) * HD + (c0 & 3) * 8;
  const unsigned short* bk1 = Wkb + (brow0 + (c1 >> 2)) * HD + (c1 & 3) * 8;
  const unsigned short* bv0 = Wvb + (brow0 + (c0 >> 2)) * HD + (c0 & 3) * 8;
  const unsigned short* bv1 = Wvb + (brow0 + (c1 >> 2)) * HD + (c1 & 3) * 8;

  f32x4 acck[4][4], accv[4][4];
  for (int i = 0; i < 4; i++)
    for (int j = 0; j < 4; j++) {
      acck[i][j] = (f32x4){0.f, 0.f, 0.f, 0.f};
      accv[i][j] = (f32x4){0.f, 0.f, 0.f, 0.f};
    }

  for (int kk = 0; kk < 32; ++kk) {
    const int k0 = kk * 32;
    __syncthreads();
    glds16(bk0 + k0, lds_bk + c0 * 8);
    glds16(bk1 + k0, lds_bk + c1 * 8);
    glds16(bv0 + k0, lds_bv + c0 * 8);
    glds16(bv1 + k0, lds_bv + c1 * 8);
    {
      float4 x0 = *(const float4*)(a0 + k0), y0 = *(const float4*)(a0 + k0 + 4);
      float4 x1 = *(const float4*)(a1 + k0), y1 = *(const float4*)(a1 + k0 + 4);
      *(uint4*)(lds_a + c0 * 8) = pack8(x0, y0);
      *(uint4*)(lds_a + c1 * 8) = pack8(x1, y1);
    }
    __syncthreads();
    bf16x8 af[4], bkf[4], bvf[4];
    for (int mt = 0; mt < 4; ++mt)
      af[mt] = *(const bf16x8*)(lds_a + (wm * 64 + mt * 16 + lr) * 32 + lq * 8);
    for (int nt = 0; nt < 4; ++nt) {
      bkf[nt] = *(const bf16x8*)(lds_bk + (wn * 64 + nt * 16 + lr) * 32 + lq * 8);
      bvf[nt] = *(const bf16x8*)(lds_bv + (wn * 64 + nt * 16 + lr) * 32 + lq * 8);
    }
    for (int mt = 0; mt < 4; ++mt)
      for (int nt = 0; nt < 4; ++nt) {
        acck[mt][nt] = __builtin_amdgcn_mfma_f32_16x16x32_bf16(af[mt], bkf[nt], acck[mt][nt], 0, 0, 0);
        accv[mt][nt] = __builtin_amdgcn_mfma_f32_16x16x32_bf16(af[mt], bvf[nt], accv[mt][nt], 0, 0, 0);
      }
  }

  for (int nt = 0; nt < 4; ++nt) {
    int n = nblk * 128 + wn * 64 + nt * 16 + lr;
    float bkk = bk[n], bvv = bv[n];
    int h = n >> 6, d = n & 63;
    for (int mt = 0; mt < 4; ++mt) {
      size_t mbase = arow0 + wm * 64 + mt * 16 + lq * 4;
      for (int r = 0; r < 4; ++r)
        Kp[(mbase + r) * HD + n] = f2bf(acck[mt][nt][r] + bkk);
      size_t bc = mbase >> 8, j = mbase & 255;
      *(ushort4*)(Vt + ((bc * 16 + h) * 64 + d) * 256 + j) =
          make_ushort4(f2bf(accv[mt][nt][0] + bvv), f2bf(accv[mt][nt][1] + bvv),
                       f2bf(accv[mt][nt][2] + bvv), f2bf(accv[mt][nt][3] + bvv));
    }
  }
}

// ---------------- Q GEMM: fp32 query (remap+pad) -> Qp bf16 ----------------
__global__ __launch_bounds__(256, 2) void gemm_q_kernel(
    const float* __restrict__ A, const unsigned short* __restrict__ Wqb,
    const float* __restrict__ bq, unsigned short* __restrict__ Qp) {
  __shared__ unsigned short lds_a[128 * 32];
  __shared__ unsigned short lds_b[128 * 32];
  const int t = threadIdx.x;
  const int l = t & 63, w = t >> 6;
  const int wm = w >> 1, wn = w & 1;
  const int lr = l & 15, lq = l >> 4;
  const int bid = blockIdx.x;  // 512 = 8 XCD x (8 M x 8 N)
  const int xcd = bid & 7, local = bid >> 3;
  const int nblk = local & 7, mblk = xcd * 8 + (local >> 3);
  const size_t arow0 = (size_t)mblk * 128;
  const size_t brow0 = (size_t)nblk * 128;
  const int c0 = t, c1 = 256 + t;
  const unsigned short* b0 = Wqb + (brow0 + (c0 >> 2)) * HD + (c0 & 3) * 8;
  const unsigned short* b1 = Wqb + (brow0 + (c1 >> 2)) * HD + (c1 & 3) * 8;
  // remap: global row g -> query row (g&2047)+63 in batch g>>11, zero if (g&2047)>=1985
  size_t g0 = arow0 + (c0 >> 2), g1 = arow0 + (c1 >> 2);
  int t0 = (int)(g0 & 2047), t1 = (int)(g1 & 2047);
  bool v0 = t0 < 1985, v1 = t1 < 1985;
  const float* a0 = A + ((g0 & ~(size_t)2047) + t0 + 63) * HD + (c0 & 3) * 8;
  const float* a1 = A + ((g1 & ~(size_t)2047) + t1 + 63) * HD + (c1 & 3) * 8;

  f32x4 acc[4][4];
  for (int i = 0; i < 4; i++)
    for (int j = 0; j < 4; j++) acc[i][j] = (f32x4){0.f, 0.f, 0.f, 0.f};

  for (int kk = 0; kk < 32; ++kk) {
    const int k0 = kk * 32;
    __syncthreads();
    glds16(b0 + k0, lds_b + c0 * 8);
    glds16(b1 + k0, lds_b + c1 * 8);
    {
      uint4 p0 = make_uint4(0, 0, 0, 0), p1 = make_uint4(0, 0, 0, 0);
      if (v0) p0 = pack8(*(const float4*)(a0 + k0), *(const float4*)(a0 + k0 + 4));
      if (v1) p1 = pack8(*(const float4*)(a1 + k0), *(const float4*)(a1 + k0 + 4));
      *(uint4*)(lds_a + c0 * 8) = p0;
      *(uint4*)(lds_a + c1 * 8) = p1;
    }
    __syncthreads();
    bf16x8 af[4], bfr[4];
    for (int mt = 0; mt < 4; ++mt)
      af[mt] = *(const bf16x8*)(lds_a + (wm * 64 + mt * 16 + lr) * 32 + lq * 8);
    for (int nt = 0; nt < 4; ++nt)
      bfr[nt] = *(const bf16x8*)(lds_b + (wn * 64 + nt * 16 + lr) * 32 + lq * 8);
    for (int mt = 0; mt < 4; ++mt)
      for (int nt = 0; nt < 4; ++nt)
        acc[mt][nt] = __builtin_amdgcn_mfma_f32_16x16x32_bf16(af[mt], bfr[nt], acc[mt][nt], 0, 0, 0);
  }

  for (int nt = 0; nt < 4; ++nt) {
    int n = nblk * 128 + wn * 64 + nt * 16 + lr;
    float bvv = bq[n];
    for (int mt = 0; mt < 4; ++mt) {
      size_t mbase = arow0 + wm * 64 + mt * 16 + lq * 4;
      for (int r = 0; r < 4; ++r)
        Qp[(mbase + r) * HD + n] = f2bf(acc[mt][nt][r] + bvv);
    }
  }
}

// ---------------- fused attention per (b, c, head); V read direct from Vt ----------------
#define QK_STRIDE 68
#define P_STRIDE 260

__global__ __launch_bounds__(256, 3) void attn_kernel(
    const unsigned short* __restrict__ Qp, const unsigned short* __restrict__ Kp,
    const unsigned short* __restrict__ Vt, float* __restrict__ out) {
  __shared__ unsigned short q_s[64 * QK_STRIDE];
  __shared__ unsigned short k_s[256 * QK_STRIDE];  // P overlay 64x260 fits
  const int t = threadIdx.x;
  const int l = t & 63, w = t >> 6;
  const int lr = l & 15, lq = l >> 4;
  const int bid = blockIdx.x;
  const int head = bid & 15, cc = (bid >> 4) & 31, b = bid >> 9;
  const size_t qrow0 = (size_t)(b * NC + cc) * 64;
  const size_t kvrow0 = (size_t)(b * NC + cc) * 256;
  const int hcol = head * 64;
  const unsigned short* vbase = Vt + ((size_t)((b * NC + cc) * 16 + head) * 64) * 256;

  for (int p = 0; p < 4; ++p) {
    int chunk = p * 256 + t;
    int row = chunk >> 4, c4 = (chunk & 15) * 4;
    *(uint2*)(q_s + row * QK_STRIDE + c4) = *(const uint2*)(Qp + (qrow0 + row) * HD + hcol + c4);
  }
  for (int p = 0; p < 16; ++p) {
    int chunk = p * 256 + t;
    int row = chunk >> 4, c4 = (chunk & 15) * 4;
    *(uint2*)(k_s + row * QK_STRIDE + c4) = *(const uint2*)(Kp + (kvrow0 + row) * HD + hcol + c4);
  }
  __syncthreads();

  bf16x8 qa0 = ld_frag8(q_s + (w * 16 + lr) * QK_STRIDE + lq * 8);
  bf16x8 qa1 = ld_frag8(q_s + (w * 16 + lr) * QK_STRIDE + 32 + lq * 8);
  f32x4 sc[16];
  for (int nt = 0; nt < 16; ++nt) {
    bf16x8 kb0 = ld_frag8(k_s + (nt * 16 + lr) * QK_STRIDE + lq * 8);
    bf16x8 kb1 = ld_frag8(k_s + (nt * 16 + lr) * QK_STRIDE + 32 + lq * 8);
    f32x4 a = (f32x4){0.f, 0.f, 0.f, 0.f};
    a = __builtin_amdgcn_mfma_f32_16x16x32_bf16(qa0, kb0, a, 0, 0, 0);
    a = __builtin_amdgcn_mfma_f32_16x16x32_bf16(qa1, kb1, a, 0, 0, 0);
    sc[nt] = a;
  }
  float mrow[4] = {-1e30f, -1e30f, -1e30f, -1e30f};
  for (int nt = 0; nt < 16; ++nt)
    for (int r = 0; r < 4; ++r) mrow[r] = fmaxf(mrow[r], sc[nt][r]);
  for (int off = 1; off < 16; off <<= 1)
    for (int r = 0; r < 4; ++r) mrow[r] = fmaxf(mrow[r], __shfl_xor(mrow[r], off, 16));
  float srow[4] = {0.f, 0.f, 0.f, 0.f};
  const float cexp = 0.18033688011112042f;  // log2(e)/8
  for (int nt = 0; nt < 16; ++nt)
    for (int r = 0; r < 4; ++r) {
      float p = exp2f((sc[nt][r] - mrow[r]) * cexp);
      sc[nt][r] = p;
      srow[r] += p;
    }
  for (int off = 1; off < 16; off <<= 1)
    for (int r = 0; r < 4; ++r) srow[r] += __shfl_xor(srow[r], off, 16);

  __syncthreads();

  for (int nt = 0; nt < 16; ++nt)
    for (int r = 0; r < 4; ++r)
      k_s[(w * 16 + lq * 4 + r) * P_STRIDE + nt * 16 + lr] = f2bf(sc[nt][r]);

  f32x4 o[4];
  for (int i = 0; i < 4; ++i) o[i] = (f32x4){0.f, 0.f, 0.f, 0.f};
  for (int ks = 0; ks < 8; ++ks) {
    bf16x8 pa = ld_frag8(k_s + (w * 16 + lr) * P_STRIDE + ks * 32 + lq * 8);
    for (int nt2 = 0; nt2 < 4; ++nt2) {
      bf16x8 vb = *(const bf16x8*)(vbase + (size_t)(nt2 * 16 + lr) * 256 + ks * 32 + lq * 8);
      o[nt2] = __builtin_amdgcn_mfma_f32_16x16x32_bf16(pa, vb, o[nt2], 0, 0, 0);
    }
  }

  for (int r = 0; r < 4; ++r) {
    int strip = w * 16 + lq * 4 + r;
    int trow = cc * 64 + strip;
    if (trow < 1985) {
      size_t orow = (size_t)b * SEQ + trow + 63;
      float inv = 1.0f / srow[r];
      for (int nt2 = 0; nt2 < 4; ++nt2)
        out[orow * HD + hcol + nt2 * 16 + lr] = o[nt2][r] * inv;
    }
  }
}

extern "C" void kernel_launch(void* const* d_in, const int* in_sizes, int n_in,
                              void* d_out, int out_size, void* d_ws, size_t ws_size,
                              hipStream_t stream) {
  (void)in_sizes; (void)n_in; (void)out_size; (void)ws_size;
  const float* query = (const float*)d_in[0];
  const float* kv    = (const float*)d_in[1];
  const float* Wq    = (const float*)d_in[2];
  const float* bq    = (const float*)d_in[3];
  const float* Wk    = (const float*)d_in[4];
  const float* bk    = (const float*)d_in[5];
  const float* Wv    = (const float*)d_in[6];
  const float* bv    = (const float*)d_in[7];
  float* out = (float*)d_out;

  unsigned short* Qp  = (unsigned short*)d_ws;          // 8192x1024 bf16
  unsigned short* Kp  = Qp + (size_t)8192 * 1024;       // 32768x1024 bf16
  unsigned short* Vt  = Kp + (size_t)32768 * 1024;      // 32768x1024 bf16 (transposed)
  unsigned short* Wqb = Vt + (size_t)32768 * 1024;      // 1024x1024 bf16
  unsigned short* Wkb = Wqb + (size_t)1024 * 1024;
  unsigned short* Wvb = Wkb + (size_t)1024 * 1024;

  zero_head_kernel<<<dim3(252), dim3(256), 0, stream>>>(out);
  cvt_kernel<<<dim3(512), dim3(256), 0, stream>>>(Wq, Wqb, 131072);
  cvt_kernel<<<dim3(512), dim3(256), 0, stream>>>(Wk, Wkb, 131072);
  cvt_kernel<<<dim3(512), dim3(256), 0, stream>>>(Wv, Wvb, 131072);
  gemm_q_kernel<<<dim3(512), dim3(256), 0, stream>>>(query, Wqb, bq, Qp);
  gemm_kv_kernel<<<dim3(2048), dim3(256), 0, stream>>>(kv, Wkb, Wvb, bk, bv, Kp, Vt);
  attn_kernel<<<dim3(2048), dim3(256), 0, stream>>>(Qp, Kp, Vt, out);
}